// Round 26
// baseline (160.053 us; speedup 1.0000x reference)
//
#include <hip/hip_runtime.h>

#define BATCH 16
#define CIN   200
#define T1    8192
#define COUTC 400
#define TT2   4096
#define NJ    25
#define NGROUP 10
#define CPG   40
#define NPOOL 14
#define CROWB 528      // conv kernel LDS row stride (33x16B, rotates bank quads)

typedef __attribute__((ext_vector_type(8))) short bf16x8;
typedef __attribute__((ext_vector_type(4))) float f32x4;

__constant__ int NBR_OFF[NJ + 1] = {0,8,14,18,21,29,35,39,42,50,56,63,72,80,85,94,101,106,110,113,122,129,134,138,141,145};
__constant__ int NBR[145] = {
 0,1,2,4,5,8,9,24,
 0,1,2,3,4,8,
 0,1,2,3,
 1,2,3,
 0,1,4,5,6,8,9,24,
 0,4,5,6,7,8,
 4,5,6,7,
 5,6,7,
 0,1,4,5,8,9,10,24,
 0,4,8,9,10,11,
 8,9,10,11,12,14,19,
 9,10,11,12,13,14,15,19,20,
 10,11,12,13,14,15,19,20,
 11,12,13,14,19,
 10,11,12,13,14,15,16,19,20,
 11,12,14,15,16,17,19,
 14,15,16,17,18,
 15,16,17,18,
 16,17,18,
 10,11,12,13,14,15,19,20,21,
 11,12,14,19,20,21,22,
 19,20,21,22,23,
 20,21,22,23,
 21,22,23,
 0,4,8,24};
__constant__ int PAIR_A[NPOOL] = {0,2,4,6,8,10,12,14,15,17,19,20,22,24};
__constant__ int PAIR_B[NPOOL] = {1,3,5,7,9,11,13,-1,16,18,-1,21,23,-1};
__constant__ int JSPLIT8[9] = {0,3,6,9,12,15,18,21,25};   // conv1 8-wave joint groups
// conv0 8-wave pool groups (balanced by nmf): sums 12,10,10,10,10,9,8,7
__constant__ int POOL_ORD[14] = {8,11, 0,1, 2,3, 4,9, 10,12, 6,13, 5, 7};
__constant__ int GB8[9] = {0,2,4,6,8,10,12,13,14};
// conv0 pair-union tables (variable-stride, round-14 layout)
__constant__ int PUOFF[15] = {0,9,13,22,26,35,45,53,62,70,74,83,91,95,99};
__constant__ int PU[99] = {
 0,1,2,3,4,5,8,9,24,
 0,1,2,3,
 0,1,4,5,6,7,8,9,24,
 4,5,6,7,
 0,1,4,5,8,9,10,11,24,
 8,9,10,11,12,13,14,15,19,20,
 10,11,12,13,14,15,19,20,
 10,11,12,13,14,15,16,19,20,
 11,12,14,15,16,17,18,19,
 15,16,17,18,
 10,11,12,13,14,15,19,20,21,
 11,12,14,19,20,21,22,23,
 20,21,22,23,
 0,4,8,24};
__constant__ int PNMF[NPOOL] = {7,3,7,3,7,8,6,7,6,3,7,6,3,3};
__constant__ int FB0[NPOOL]  = {0,7,10,17,20,27,35,41,48,54,57,64,70,73};  // total 76
__constant__ int FRAG_P[76] = {
 0,0,0,0,0,0,0, 1,1,1, 2,2,2,2,2,2,2, 3,3,3, 4,4,4,4,4,4,4, 5,5,5,5,5,5,5,5,
 6,6,6,6,6,6, 7,7,7,7,7,7,7, 8,8,8,8,8,8, 9,9,9, 10,10,10,10,10,10,10,
 11,11,11,11,11,11, 12,12,12, 13,13,13};
// shortcut fragment tables (variable-stride, round-14 layout)
__constant__ int NSF[NJ] = {2,2,1,1,2,2,1,1,2,2,2,3,2,2,3,2,2,1,1,3,2,2,1,1,1};
__constant__ int FBS[NJ] = {0,2,4,5,6,8,10,11,12,14,16,18,21,23,25,28,30,32,33,34,37,39,41,42,43}; // total 44
__constant__ int FRAG_SJ[44] = {
 0,0, 1,1, 2, 3, 4,4, 5,5, 6, 7, 8,8, 9,9, 10,10, 11,11,11, 12,12, 13,13,
 14,14,14, 15,15, 16,16, 17, 18, 19,19,19, 20,20, 21,21, 22, 23, 24};
// conv1 fixed-stride layout: 7 frags/joint
#define NF1   (NJ * 7)       // 175
#define DSC_SC   304                  // shortcut desc base (76*4)
#define DSC_C1   480                  // conv1 desc base (304 + 44*4)
#define DSC_TOT  (DSC_C1 + NF1 * 4)   // 1180

// ---- bf16 helpers ----
__device__ __forceinline__ unsigned bfround(float f) {
    unsigned u = __builtin_bit_cast(unsigned, f);
    return (u + 0x7FFFu + ((u >> 16) & 1u)) >> 16;
}
__device__ __forceinline__ unsigned packbf(float lo, float hi) {
    return bfround(lo) | (bfround(hi) << 16);
}
__device__ __forceinline__ float bflo(unsigned u) { return __builtin_bit_cast(float, u << 16); }
__device__ __forceinline__ float bfhi(unsigned u) { return __builtin_bit_cast(float, u & 0xFFFF0000u); }

// ------- merged prep: [0,NF1) conv1 w; [NF1,NF1+76) conv0 w; [+44) shortcut w;
//         last block: descriptors ------------------------------------------------
__global__ void prep_all(const float* __restrict__ w1, const float* __restrict__ w0,
                         const float* __restrict__ wsc,
                         unsigned short* __restrict__ wA1, unsigned short* __restrict__ wA0,
                         unsigned short* __restrict__ wAs, int* __restrict__ dsc)
{
    const int bid = blockIdx.x;
    if (bid < NF1) {                               // conv1 weights
        const int f  = bid;
        const int jo = f / 7;
        const int mf = f - jo * 7;
        const int off = NBR_OFF[jo];
        const int deg = NBR_OFF[jo + 1] - off;
        for (int e = threadIdx.x; e < 512; e += 256) {
            int lane = e >> 3, j = e & 7;
            int m = lane & 15, kb = lane >> 4;
            int c8 = mf * 4 + kb;
            float v = 0.f;
            if (c8 < 3 * deg) {
                int tap = (c8 >= 2 * deg) ? 2 : ((c8 >= deg) ? 1 : 0);
                int nbr_i = c8 - tap * deg;
                int ci = NBR[off + nbr_i] * 8 + j;
                v = w1[(size_t)(jo * 16 + m) * 600 + ci * 3 + tap];
            }
            wA1[(size_t)f * 512 + e] = (unsigned short)bfround(v);
        }
    } else if (bid < NF1 + 76) {                   // conv0 pair weights
        const int f  = bid - NF1;
        const int p  = FRAG_P[f];
        const int mf = f - FB0[p];
        const int puo = PUOFF[p];
        const int u   = PUOFF[p + 1] - puo;
        for (int e = threadIdx.x; e < 512; e += 256) {
            int lane = e >> 3, j = e & 7;
            int m = lane & 15, kb = lane >> 4;
            int c8 = mf * 4 + kb;
            int jm = (m < 8) ? PAIR_A[p] : PAIR_B[p];
            float v = 0.f;
            if (c8 < 3 * u && jm >= 0) {
                int tap = (c8 >= 2 * u) ? 2 : ((c8 >= u) ? 1 : 0);
                int ni  = c8 - tap * u;
                int nbr = PU[puo + ni];
                int offj = NBR_OFF[jm], degj = NBR_OFF[jm + 1] - offj;
                bool mem = false;
                for (int s = 0; s < degj; ++s) mem = mem || (NBR[offj + s] == nbr);
                if (mem) {
                    int ci = nbr * 8 + j;
                    v = w0[(size_t)(jm * 8 + (m & 7)) * 600 + ci * 3 + tap];
                }
            }
            wA0[(size_t)f * 512 + e] = (unsigned short)bfround(v);
        }
    } else if (bid < NF1 + 76 + 44) {              // shortcut weights
        const int f  = bid - NF1 - 76;
        const int jo = FRAG_SJ[f];
        const int mf = f - FBS[jo];
        const int off = NBR_OFF[jo];
        const int deg = NBR_OFF[jo + 1] - off;
        for (int e = threadIdx.x; e < 512; e += 256) {
            int lane = e >> 3, j = e & 7;
            int m = lane & 15, kb = lane >> 4;
            int c8 = mf * 4 + kb;
            float v = 0.f;
            if (c8 < deg) {
                int ci = NBR[off + c8] * 8 + j;
                v = wsc[(size_t)(jo * 16 + m) * 200 + ci];
            }
            wAs[(size_t)f * 512 + e] = (unsigned short)bfround(v);
        }
    } else {                                       // descriptors
        for (int e = threadIdx.x; e < DSC_TOT; e += 256) {
            if (e < DSC_SC) {
                int f = e >> 2, q = e & 3;
                int p = FRAG_P[f], mf = f - FB0[p];
                int puo = PUOFF[p], u = PUOFF[p + 1] - puo;
                int c8 = mf * 4 + q;
                int tp = 0, ni = 0;
                if (c8 < 3 * u) {
                    tp = (c8 >= 2 * u) ? 2 : ((c8 >= u) ? 1 : 0);
                    ni = c8 - tp * u;
                }
                dsc[e] = (tp << 12) | (PU[puo + ni] * 16);
            } else if (e < DSC_C1) {
                int e2 = e - DSC_SC;
                int f = e2 >> 2, q = e2 & 3;
                int jo = FRAG_SJ[f], mf = f - FBS[jo];
                int off = NBR_OFF[jo], deg = NBR_OFF[jo + 1] - off;
                int c8 = mf * 4 + q;
                int ni = (c8 < deg) ? c8 : deg - 1;
                dsc[e] = NBR[off + ni] * 16;
            } else {
                int e2 = e - DSC_C1;
                int f = e2 >> 2, q = e2 & 3;
                int jo = f / 7, mf = f - jo * 7;
                int off = NBR_OFF[jo], deg = NBR_OFF[jo + 1] - off;
                int c8 = mf * 4 + q;
                int tp = 0, ni = 0;
                if (c8 < 3 * deg) {
                    tp = (c8 >= 2 * deg) ? 2 : ((c8 >= deg) ? 1 : 0);
                    ni = c8 - tp * deg;
                }
                int rowd = (tp == 1) ? 33 : (tp >> 1);
                dsc[e] = rowd * CROWB + NBR[off + ni] * 16;
            }
        }
    }
}

// ------- Kernel A: conv0 + PReLU + shortcut via MFMA; 8-wave, 4 subtiles per A ---
// grid (128, 16), block 512 (8 waves = 8 pool groups; each wave all 4 subtiles).
__global__ __launch_bounds__(512) void conv0s_mfma(
    const float* __restrict__ x, const unsigned short* __restrict__ wA0,
    const unsigned short* __restrict__ wAs, const int* __restrict__ dsc,
    const float* __restrict__ b0, const float* __restrict__ a0,
    const float* __restrict__ bsc,
    unsigned short* __restrict__ h0T, unsigned short* __restrict__ sbu)
{
    __shared__ __align__(16) unsigned short xs[66 * 264];
    __shared__ int dl[DSC_C1];
    __shared__ float b0l[CIN], bscl[COUTC];
    const int b   = blockIdx.y;
    const int t0  = blockIdx.x * 64;
    const int tid = threadIdx.x;

    for (int i = tid; i < DSC_C1; i += 512) dl[i] = dsc[i];
    for (int i = tid; i < CIN; i += 512) b0l[i] = b0[i];
    for (int i = tid; i < COUTC; i += 512) bscl[i] = bsc[i];

    // ---- fused staging: x fp32 [c][t] -> xs bf16 [t=row][c], rows 0..65 ----
    const float* xb = x + (size_t)b * CIN * T1;
    // main rows 1..64: 8 channels x 4 t per thread, uint4 (16B) writes
    for (int e = tid; e < (CIN / 8) * 16; e += 512) {
        int c8i = e >> 4, k = e & 15;
        const float* xc = xb + (size_t)(8 * c8i) * T1 + t0 + 4 * k;
        float4 v0 = *(const float4*)(xc);
        float4 v1 = *(const float4*)(xc + T1);
        float4 v2 = *(const float4*)(xc + 2 * T1);
        float4 v3 = *(const float4*)(xc + 3 * T1);
        float4 v4 = *(const float4*)(xc + 4 * T1);
        float4 v5 = *(const float4*)(xc + 5 * T1);
        float4 v6 = *(const float4*)(xc + 6 * T1);
        float4 v7 = *(const float4*)(xc + 7 * T1);
        char* base = (char*)xs + 16 * c8i + (4 * k + 1) * CROWB;
        *(uint4*)(base) = make_uint4(packbf(v0.x, v1.x), packbf(v2.x, v3.x),
                                     packbf(v4.x, v5.x), packbf(v6.x, v7.x));
        *(uint4*)(base + CROWB) = make_uint4(packbf(v0.y, v1.y), packbf(v2.y, v3.y),
                                             packbf(v4.y, v5.y), packbf(v6.y, v7.y));
        *(uint4*)(base + 2 * CROWB) = make_uint4(packbf(v0.z, v1.z), packbf(v2.z, v3.z),
                                                 packbf(v4.z, v5.z), packbf(v6.z, v7.z));
        *(uint4*)(base + 3 * CROWB) = make_uint4(packbf(v0.w, v1.w), packbf(v2.w, v3.w),
                                                 packbf(v4.w, v5.w), packbf(v6.w, v7.w));
    }
    // halo rows 0 (t0-1) and 65 (t0+64), reflect-clamped
    for (int e = tid; e < 2 * CIN; e += 512) {
        int c = e >> 1, h = e & 1;
        int t = h ? (t0 + 64) : (t0 - 1);
        t = (t < 0) ? 1 : ((t >= T1) ? (2 * T1 - 2 - t) : t);
        float v = xb[(size_t)c * T1 + t];
        *(unsigned short*)((char*)xs + (h ? 65 : 0) * CROWB + 2 * c) = (unsigned short)bfround(v);
    }
    __syncthreads();

    const int w = tid >> 6, lane = tid & 63;
    const int q = lane >> 4, n = lane & 15;
    const float alpha = a0[0];
    char* xsb = (char*)xs + n * CROWB;

    // ---- conv0: pool group GB8[w]..GB8[w+1] x rotating depth-2 (A+B) x 4 subtiles
    unsigned h0k[2][4][2];
    const int g0 = GB8[w], g1 = GB8[w + 1];
    for (int gi = g0, pl = 0; gi < g1; ++gi, ++pl) {
        const int p = POOL_ORD[gi];
        const int fb = FB0[p], nmf = PNMF[p];
        const unsigned short* wAb = wA0 + (size_t)fb * 512;
        f32x4 acc0 = {0.f, 0.f, 0.f, 0.f};
        f32x4 acc1 = {0.f, 0.f, 0.f, 0.f};
        f32x4 acc2 = {0.f, 0.f, 0.f, 0.f};
        f32x4 acc3 = {0.f, 0.f, 0.f, 0.f};
        bf16x8 aCur = *(const bf16x8*)(wAb + (size_t)lane * 8);
        int d = dl[fb * 4 + q];
        char* bp = xsb + (d >> 12) * CROWB + (d & 0xFFF);
        bf16x8 B0c = *(const bf16x8*)(bp);
        bf16x8 B1c = *(const bf16x8*)(bp + 16 * CROWB);
        bf16x8 B2c = *(const bf16x8*)(bp + 32 * CROWB);
        bf16x8 B3c = *(const bf16x8*)(bp + 48 * CROWB);
        for (int mf = 0; mf < nmf; ++mf) {
            int m2 = (mf + 1 < nmf) ? mf + 1 : mf;
            bf16x8 aNxt = *(const bf16x8*)(wAb + ((size_t)m2 * 64 + lane) * 8);
            d = dl[(fb + m2) * 4 + q];
            char* bpn = xsb + (d >> 12) * CROWB + (d & 0xFFF);
            bf16x8 B0n = *(const bf16x8*)(bpn);
            bf16x8 B1n = *(const bf16x8*)(bpn + 16 * CROWB);
            bf16x8 B2n = *(const bf16x8*)(bpn + 32 * CROWB);
            bf16x8 B3n = *(const bf16x8*)(bpn + 48 * CROWB);
            __builtin_amdgcn_s_setprio(1);
            acc0 = __builtin_amdgcn_mfma_f32_16x16x32_bf16(aCur, B0c, acc0, 0, 0, 0);
            acc1 = __builtin_amdgcn_mfma_f32_16x16x32_bf16(aCur, B1c, acc1, 0, 0, 0);
            acc2 = __builtin_amdgcn_mfma_f32_16x16x32_bf16(aCur, B2c, acc2, 0, 0, 0);
            acc3 = __builtin_amdgcn_mfma_f32_16x16x32_bf16(aCur, B3c, acc3, 0, 0, 0);
            __builtin_amdgcn_s_setprio(0);
            aCur = aNxt;
            B0c = B0n; B1c = B1n; B2c = B2n; B3c = B3n;
        }
        int jm = (q < 2) ? PAIR_A[p] : PAIR_B[p];
        if (jm >= 0) {
            int ocb = (q & 1) * 4;
            float bb0 = b0l[jm * 8 + ocb + 0], bb1 = b0l[jm * 8 + ocb + 1];
            float bb2 = b0l[jm * 8 + ocb + 2], bb3 = b0l[jm * 8 + ocb + 3];
            f32x4 aa[4] = {acc0, acc1, acc2, acc3};
#pragma unroll
            for (int s = 0; s < 4; ++s) {
                float v0 = aa[s][0] + bb0; v0 = (v0 >= 0.f) ? v0 : alpha * v0;
                float v1 = aa[s][1] + bb1; v1 = (v1 >= 0.f) ? v1 : alpha * v1;
                float v2 = aa[s][2] + bb2; v2 = (v2 >= 0.f) ? v2 : alpha * v2;
                float v3 = aa[s][3] + bb3; v3 = (v3 >= 0.f) ? v3 : alpha * v3;
                h0k[pl][s][0] = packbf(v0, v1);
                h0k[pl][s][1] = packbf(v2, v3);
            }
        }
    }

    // ---- shortcut: joints mod 8 per wave, rotating depth-2, both ns-halves ----
    for (int jo = w; jo < NJ; jo += 8) {
        const int fb = FBS[jo], nsf = NSF[jo];
        const unsigned short* wAb = wAs + (size_t)fb * 512;
        const int dbase = DSC_SC + fb * 4 + q;
        char* rb0 = (char*)xs + (2 * n + 1) * CROWB;
        f32x4 acc0 = {0.f, 0.f, 0.f, 0.f};
        f32x4 acc1 = {0.f, 0.f, 0.f, 0.f};
        int i1 = (nsf > 1) ? 1 : 0;
        bf16x8 af0 = *(const bf16x8*)(wAb + (size_t)lane * 8);
        int d = dl[dbase];
        bf16x8 b0v = *(const bf16x8*)(rb0 + d);
        bf16x8 b1v = *(const bf16x8*)(rb0 + d + 32 * CROWB);
        bf16x8 af1 = *(const bf16x8*)(wAb + ((size_t)i1 * 64 + lane) * 8);
        d = dl[dbase + i1 * 4];
        bf16x8 b0n = *(const bf16x8*)(rb0 + d);
        bf16x8 b1n = *(const bf16x8*)(rb0 + d + 32 * CROWB);
        for (int mf = 0; mf < nsf; ++mf) {
            int m2 = (mf + 2 < nsf) ? mf + 2 : nsf - 1;
            bf16x8 a2 = *(const bf16x8*)(wAb + ((size_t)m2 * 64 + lane) * 8);
            d = dl[dbase + m2 * 4];
            bf16x8 b02 = *(const bf16x8*)(rb0 + d);
            bf16x8 b12 = *(const bf16x8*)(rb0 + d + 32 * CROWB);
            __builtin_amdgcn_s_setprio(1);
            acc0 = __builtin_amdgcn_mfma_f32_16x16x32_bf16(af0, b0v, acc0, 0, 0, 0);
            acc1 = __builtin_amdgcn_mfma_f32_16x16x32_bf16(af0, b1v, acc1, 0, 0, 0);
            __builtin_amdgcn_s_setprio(0);
            af0 = af1; af1 = a2;
            b0v = b0n; b0n = b02;
            b1v = b1n; b1n = b12;
        }
        unsigned short* sp = sbu + ((size_t)b * COUTC + jo * 16 + q * 4) * TT2 + (t0 >> 1) + n;
#pragma unroll
        for (int r = 0; r < 4; ++r) {
            float bsv = bscl[jo * 16 + q * 4 + r];
            sp[(size_t)r * TT2]      = (unsigned short)bfround(acc0[r] + bsv);
            sp[(size_t)r * TT2 + 16] = (unsigned short)bfround(acc1[r] + bsv);
        }
    }

    // ---- write h0 tile into xs as [t][c] (uint2 8B writes), store h0T coalesced --
    __syncthreads();
    for (int gi = g0, pl = 0; gi < g1; ++gi, ++pl) {
        int p = POOL_ORD[gi];
        int jm = (q < 2) ? PAIR_A[p] : PAIR_B[p];
        if (jm >= 0) {
            int cb = (jm * 8 + (q & 1) * 4) * 2;
#pragma unroll
            for (int s = 0; s < 4; ++s)
                *(uint2*)((char*)xs + (16 * s + n) * CROWB + cb) =
                    make_uint2(h0k[pl][s][0], h0k[pl][s][1]);
        }
    }
    __syncthreads();
    unsigned short* ho = h0T + ((size_t)b * T1 + t0 + w * 8) * CIN;
    for (int e = lane; e < 8 * 25; e += 64) {
        int row = e / 25, k = e - row * 25;
        uint4 u = *(const uint4*)((char*)xs + (w * 8 + row) * CROWB + 16 * k);
        *(uint4*)(ho + (size_t)row * CIN + 8 * k) = u;
    }
}

// ------- Kernel B: conv1 via MFMA + GN partials; 8-wave blocks -------------------
// grid (128, 16), block 512 (8 waves = joint groups; each wave both t2-subtiles).
__global__ __launch_bounds__(512) void conv1_mfma(
    const unsigned short* __restrict__ h0T, const unsigned short* __restrict__ wA,
    const int* __restrict__ dsc, const float* __restrict__ b1,
    unsigned short* __restrict__ h1u, float* __restrict__ part)
{
    __shared__ __align__(16) unsigned short xs[65 * 264];   // odd rows 0..32, even 33..64
    __shared__ int dl1[NF1 * 4];
    __shared__ float biasl[COUTC];
    const int b   = blockIdx.y;
    const int t20 = blockIdx.x * 32;
    const int tid = threadIdx.x;

    for (int i = tid; i < NF1 * 4; i += 512) dl1[i] = dsc[DSC_C1 + i];
    for (int i = tid; i < COUTC; i += 512) biasl[i] = b1[i];

    const unsigned short* hTb = h0T + (size_t)b * T1 * CIN;
    for (int e = tid; e < 65 * 25; e += 512) {
        int row = e / 25, k = e - row * 25;
        int p = (row < 33) ? (2 * t20 - 1 + 2 * row) : (2 * t20 + 2 * (row - 33));
        if (p < 0) p = 1;
        uint4 u = *(const uint4*)(hTb + (size_t)p * CIN + 8 * k);
        *(uint4*)((char*)xs + row * CROWB + 16 * k) = u;
    }
    __syncthreads();

    const int w = tid >> 6, lane = tid & 63;
    const int q = lane >> 4, n = lane & 15;
    const int j0 = JSPLIT8[w], j1 = JSPLIT8[w + 1];
    const int t2gA = t20 + n, t2gB = t20 + 16 + n;
    char* xsb = (char*)xs + n * CROWB;

    for (int jo = j0; jo < j1; ++jo) {
        const unsigned short* wAb = wA + (size_t)(jo * 7) * 512;
        const int dbase = jo * 28 + q;
        f32x4 acc0 = {0.f, 0.f, 0.f, 0.f};
        f32x4 acc1 = {0.f, 0.f, 0.f, 0.f};
#pragma unroll
        for (int mf = 0; mf < 7; ++mf) {
            bf16x8 a = *(const bf16x8*)(wAb + ((size_t)mf * 64 + lane) * 8);
            int d = dl1[dbase + mf * 4];
            bf16x8 bb0 = *(const bf16x8*)(xsb + d);
            bf16x8 bb1 = *(const bf16x8*)(xsb + d + 16 * CROWB);
            __builtin_amdgcn_s_setprio(1);
            acc0 = __builtin_amdgcn_mfma_f32_16x16x32_bf16(a, bb0, acc0, 0, 0, 0);
            acc1 = __builtin_amdgcn_mfma_f32_16x16x32_bf16(a, bb1, acc1, 0, 0, 0);
            __builtin_amdgcn_s_setprio(0);
        }

        float s = 0.f, ss = 0.f;
        unsigned short* hout = h1u + ((size_t)b * COUTC + jo * 16) * TT2;
#pragma unroll
        for (int r = 0; r < 4; ++r) {
            int oc = q * 4 + r;
            float bv = biasl[jo * 16 + oc];
            float v0 = acc0[r] + bv;
            float v1 = acc1[r] + bv;
            s += v0 + v1; ss += v0 * v0 + v1 * v1;
            hout[(size_t)oc * TT2 + t2gA] = (unsigned short)bfround(v0);
            hout[(size_t)oc * TT2 + t2gB] = (unsigned short)bfround(v1);
        }
        for (int o2 = 1; o2 < 32; o2 <<= 1) {
            s  += __shfl_xor(s, o2, 64);
            ss += __shfl_xor(ss, o2, 64);
        }
        if ((lane & 31) == 0) {
            int half = lane >> 5;
            size_t o = (((size_t)b * 50 + jo * 2 + half) * 128 + blockIdx.x) * 2;
            part[o] = s; part[o + 1] = ss;
        }
    }
}

// ------- finalize stats + per-(b,ch) GN coefficients (merged) --------------------
__global__ __launch_bounds__(256) void gn_final2(const float* __restrict__ part,
                                                 const float* __restrict__ gamma,
                                                 const float* __restrict__ beta,
                                                 float* __restrict__ AB)
{
    const int bg = blockIdx.x;
    const int b = bg / NGROUP, g = bg % NGROUP;
    float s = 0.f, ss = 0.f;
    for (int k = threadIdx.x; k < 5 * 128; k += 256) {
        int sb = k >> 7, slot = k & 127;
        size_t o = (((size_t)b * 50 + g * 5 + sb) * 128 + slot) * 2;
        s += part[o]; ss += part[o + 1];
    }
    for (int o2 = 32; o2; o2 >>= 1) {
        s  += __shfl_down(s, o2, 64);
        ss += __shfl_down(ss, o2, 64);
    }
    __shared__ float rs[4], rss[4];
    __shared__ float sm[2];
    const int lane = threadIdx.x & 63, wv = threadIdx.x >> 6;
    if (lane == 0) { rs[wv] = s; rss[wv] = ss; }
    __syncthreads();
    if (threadIdx.x == 0) {
        float S  = rs[0] + rs[1] + rs[2] + rs[3];
        float SS = rss[0] + rss[1] + rss[2] + rss[3];
        const float invN = 1.0f / (float)(CPG * TT2);
        float mean = S * invN;
        float var  = SS * invN - mean * mean;
        sm[0] = mean;
        sm[1] = rsqrtf(var + 1e-5f);
    }
    __syncthreads();
    if (threadIdx.x < CPG) {
        int ch = g * CPG + threadIdx.x;
        float A = sm[1] * gamma[ch];
        AB[((size_t)b * COUTC + ch) * 2]     = A;
        AB[((size_t)b * COUTC + ch) * 2 + 1] = beta[ch] - sm[0] * A;
    }
}

// ------- Kernel E: streaming GN-apply + add s + pool + PReLU ---------------------
__global__ __launch_bounds__(256) void final2pb(
    const unsigned* __restrict__ h1b, const unsigned* __restrict__ sb,
    const float* __restrict__ AB, const float* __restrict__ a1,
    float* __restrict__ outb)
{
    const int n     = blockIdx.y >> 1;
    const int chalf = blockIdx.y & 1;
    const int b     = blockIdx.z;
    const int tid   = threadIdx.x;
    const int t0    = (blockIdx.x * 256 + tid) * 4;

    int js[2];
    js[0] = PAIR_A[n];
    const int jb = PAIR_B[n];
    const int L = (jb >= 0) ? 2 : 1;
    js[1] = (jb >= 0) ? jb : js[0];

    __shared__ float Al[2][8], Bl[2][8];
    if (tid < 16) {
        int ji = tid >> 3, c8 = tid & 7;
        int ch = js[ji] * 16 + chalf * 8 + c8;
        Al[ji][c8] = AB[((size_t)b * COUTC + ch) * 2];
        Bl[ji][c8] = AB[((size_t)b * COUTC + ch) * 2 + 1];
    }
    __syncthreads();

    const float alpha = a1[0];
    const float invL  = (L == 2) ? 0.5f : 1.0f;

    float acc[8][4];
#pragma unroll
    for (int c = 0; c < 8; ++c)
#pragma unroll
        for (int i = 0; i < 4; ++i) acc[c][i] = 0.f;

    for (int ji = 0; ji < L; ++ji) {
        const int jc0 = js[ji] * 16 + chalf * 8;
#pragma unroll
        for (int c = 0; c < 8; ++c) {
            size_t rowoff = ((size_t)b * COUTC + jc0 + c) * (TT2 / 2) + t0 / 2;
            uint2 hv = *(const uint2*)(h1b + rowoff);
            uint2 sv = *(const uint2*)(sb + rowoff);
            float A = Al[ji][c], Bc = Bl[ji][c];
            acc[c][0] += bflo(hv.x) * A + Bc + bflo(sv.x);
            acc[c][1] += bfhi(hv.x) * A + Bc + bfhi(sv.x);
            acc[c][2] += bflo(hv.y) * A + Bc + bflo(sv.y);
            acc[c][3] += bfhi(hv.y) * A + Bc + bfhi(sv.y);
        }
    }

    float* ob = outb + ((size_t)b * 224 + n * 16 + chalf * 8) * TT2 + t0;
#pragma unroll
    for (int c = 0; c < 8; ++c) {
        float4 o;
#pragma unroll
        for (int i = 0; i < 4; ++i) {
            float v = acc[c][i] * invL;
            ((float*)&o)[i] = (v >= 0.f) ? v : alpha * v;
        }
        *(float4*)(ob + (size_t)c * TT2) = o;
    }
}

extern "C" void kernel_launch(void* const* d_in, const int* in_sizes, int n_in,
                              void* d_out, int out_size, void* d_ws, size_t ws_size,
                              hipStream_t stream) {
    const float* x     = (const float*)d_in[0];
    const float* w0    = (const float*)d_in[1];
    const float* b0    = (const float*)d_in[2];
    const float* a0    = (const float*)d_in[3];
    const float* w1    = (const float*)d_in[4];
    const float* b1    = (const float*)d_in[5];
    const float* gamma = (const float*)d_in[6];
    const float* beta  = (const float*)d_in[7];
    const float* wsc   = (const float*)d_in[8];
    const float* bsc   = (const float*)d_in[9];
    const float* a1    = (const float*)d_in[10];
    float* out = (float*)d_out;

    const size_t NB = (size_t)BATCH * CIN * T1;   // 26,214,400 elements
    unsigned short* h0T  = (unsigned short*)d_ws;
    unsigned short* sbu  = h0T + NB;
    unsigned short* h1u  = sbu + NB;
    unsigned short* wA1  = h1u + NB;                              // 175*512
    unsigned short* wA0p = wA1 + (size_t)NF1 * 512;               // 76*512
    unsigned short* wAsp = wA0p + (size_t)76 * 512;               // 44*512
    int* dsc     = (int*)(wAsp + (size_t)44 * 512);               // 1180 ints
    float* part  = (float*)(dsc + DSC_TOT);                       // 16*50*128*2
    float* AB    = part + (size_t)BATCH * 50 * 128 * 2;

    prep_all<<<dim3(NF1 + 76 + 44 + 1), 256, 0, stream>>>(w1, w0, wsc, wA1, wA0p, wAsp, dsc);
    conv0s_mfma<<<dim3(T1 / 64, BATCH), 512, 0, stream>>>(x, wA0p, wAsp, dsc, b0, a0, bsc, h0T, sbu);
    conv1_mfma<<<dim3(TT2 / 32, BATCH), 512, 0, stream>>>(h0T, wA1, dsc, b1, h1u, part);
    gn_final2<<<dim3(BATCH * NGROUP), 256, 0, stream>>>(part, gamma, beta, AB);
    final2pb<<<dim3(TT2 / 1024, NPOOL * 2, BATCH), 256, 0, stream>>>((const unsigned*)h1u,
                                                                     (const unsigned*)sbu, AB, a1, out);
}

// Round 27
// 145.836 us; speedup vs baseline: 1.0975x; 1.0975x over previous
//
#include <hip/hip_runtime.h>

#define BATCH 16
#define CIN   200
#define T1    8192
#define COUTC 400
#define TT2   4096
#define NJ    25
#define NGROUP 10
#define CPG   40
#define NPOOL 14
#define CROWB 528      // conv kernel LDS row stride (33x16B, rotates bank quads)

typedef __attribute__((ext_vector_type(8))) short bf16x8;
typedef __attribute__((ext_vector_type(4))) float f32x4;

__constant__ int NBR_OFF[NJ + 1] = {0,8,14,18,21,29,35,39,42,50,56,63,72,80,85,94,101,106,110,113,122,129,134,138,141,145};
__constant__ int NBR[145] = {
 0,1,2,4,5,8,9,24,
 0,1,2,3,4,8,
 0,1,2,3,
 1,2,3,
 0,1,4,5,6,8,9,24,
 0,4,5,6,7,8,
 4,5,6,7,
 5,6,7,
 0,1,4,5,8,9,10,24,
 0,4,8,9,10,11,
 8,9,10,11,12,14,19,
 9,10,11,12,13,14,15,19,20,
 10,11,12,13,14,15,19,20,
 11,12,13,14,19,
 10,11,12,13,14,15,16,19,20,
 11,12,14,15,16,17,19,
 14,15,16,17,18,
 15,16,17,18,
 16,17,18,
 10,11,12,13,14,15,19,20,21,
 11,12,14,19,20,21,22,
 19,20,21,22,23,
 20,21,22,23,
 21,22,23,
 0,4,8,24};
__constant__ int PAIR_A[NPOOL] = {0,2,4,6,8,10,12,14,15,17,19,20,22,24};
__constant__ int PAIR_B[NPOOL] = {1,3,5,7,9,11,13,-1,16,18,-1,21,23,-1};
__constant__ int JSPLIT8[9] = {0,3,6,9,12,15,18,21,25};   // conv1 8-wave joint groups
// conv0 8-wave pool groups (balanced by nmf): sums 12,10,10,10,10,9,8,7
__constant__ int POOL_ORD[14] = {8,11, 0,1, 2,3, 4,9, 10,12, 6,13, 5, 7};
__constant__ int GB8[9] = {0,2,4,6,8,10,12,13,14};
// conv0 pair-union tables (variable-stride, round-14 layout)
__constant__ int PUOFF[15] = {0,9,13,22,26,35,45,53,62,70,74,83,91,95,99};
__constant__ int PU[99] = {
 0,1,2,3,4,5,8,9,24,
 0,1,2,3,
 0,1,4,5,6,7,8,9,24,
 4,5,6,7,
 0,1,4,5,8,9,10,11,24,
 8,9,10,11,12,13,14,15,19,20,
 10,11,12,13,14,15,19,20,
 10,11,12,13,14,15,16,19,20,
 11,12,14,15,16,17,18,19,
 15,16,17,18,
 10,11,12,13,14,15,19,20,21,
 11,12,14,19,20,21,22,23,
 20,21,22,23,
 0,4,8,24};
__constant__ int PNMF[NPOOL] = {7,3,7,3,7,8,6,7,6,3,7,6,3,3};
__constant__ int FB0[NPOOL]  = {0,7,10,17,20,27,35,41,48,54,57,64,70,73};  // total 76
__constant__ int FRAG_P[76] = {
 0,0,0,0,0,0,0, 1,1,1, 2,2,2,2,2,2,2, 3,3,3, 4,4,4,4,4,4,4, 5,5,5,5,5,5,5,5,
 6,6,6,6,6,6, 7,7,7,7,7,7,7, 8,8,8,8,8,8, 9,9,9, 10,10,10,10,10,10,10,
 11,11,11,11,11,11, 12,12,12, 13,13,13};
// shortcut fragment tables (variable-stride, round-14 layout)
__constant__ int NSF[NJ] = {2,2,1,1,2,2,1,1,2,2,2,3,2,2,3,2,2,1,1,3,2,2,1,1,1};
__constant__ int FBS[NJ] = {0,2,4,5,6,8,10,11,12,14,16,18,21,23,25,28,30,32,33,34,37,39,41,42,43}; // total 44
__constant__ int FRAG_SJ[44] = {
 0,0, 1,1, 2, 3, 4,4, 5,5, 6, 7, 8,8, 9,9, 10,10, 11,11,11, 12,12, 13,13,
 14,14,14, 15,15, 16,16, 17, 18, 19,19,19, 20,20, 21,21, 22, 23, 24};
// conv1 fixed-stride layout: 7 frags/joint
#define NF1   (NJ * 7)       // 175
#define DSC_SC   304                  // shortcut desc base (76*4)
#define DSC_C1   480                  // conv1 desc base (304 + 44*4)
#define DSC_TOT  (DSC_C1 + NF1 * 4)   // 1180

// ---- bf16 helpers ----
__device__ __forceinline__ unsigned bfround(float f) {
    unsigned u = __builtin_bit_cast(unsigned, f);
    return (u + 0x7FFFu + ((u >> 16) & 1u)) >> 16;
}
__device__ __forceinline__ unsigned packbf(float lo, float hi) {
    return bfround(lo) | (bfround(hi) << 16);
}
__device__ __forceinline__ float bflo(unsigned u) { return __builtin_bit_cast(float, u << 16); }
__device__ __forceinline__ float bfhi(unsigned u) { return __builtin_bit_cast(float, u & 0xFFFF0000u); }

// ------- merged prep: [0,NF1) conv1 w; [NF1,NF1+76) conv0 w; [+44) shortcut w;
//         last block: descriptors ------------------------------------------------
__global__ void prep_all(const float* __restrict__ w1, const float* __restrict__ w0,
                         const float* __restrict__ wsc,
                         unsigned short* __restrict__ wA1, unsigned short* __restrict__ wA0,
                         unsigned short* __restrict__ wAs, int* __restrict__ dsc)
{
    const int bid = blockIdx.x;
    if (bid < NF1) {                               // conv1 weights
        const int f  = bid;
        const int jo = f / 7;
        const int mf = f - jo * 7;
        const int off = NBR_OFF[jo];
        const int deg = NBR_OFF[jo + 1] - off;
        for (int e = threadIdx.x; e < 512; e += 256) {
            int lane = e >> 3, j = e & 7;
            int m = lane & 15, kb = lane >> 4;
            int c8 = mf * 4 + kb;
            float v = 0.f;
            if (c8 < 3 * deg) {
                int tap = (c8 >= 2 * deg) ? 2 : ((c8 >= deg) ? 1 : 0);
                int nbr_i = c8 - tap * deg;
                int ci = NBR[off + nbr_i] * 8 + j;
                v = w1[(size_t)(jo * 16 + m) * 600 + ci * 3 + tap];
            }
            wA1[(size_t)f * 512 + e] = (unsigned short)bfround(v);
        }
    } else if (bid < NF1 + 76) {                   // conv0 pair weights
        const int f  = bid - NF1;
        const int p  = FRAG_P[f];
        const int mf = f - FB0[p];
        const int puo = PUOFF[p];
        const int u   = PUOFF[p + 1] - puo;
        for (int e = threadIdx.x; e < 512; e += 256) {
            int lane = e >> 3, j = e & 7;
            int m = lane & 15, kb = lane >> 4;
            int c8 = mf * 4 + kb;
            int jm = (m < 8) ? PAIR_A[p] : PAIR_B[p];
            float v = 0.f;
            if (c8 < 3 * u && jm >= 0) {
                int tap = (c8 >= 2 * u) ? 2 : ((c8 >= u) ? 1 : 0);
                int ni  = c8 - tap * u;
                int nbr = PU[puo + ni];
                int offj = NBR_OFF[jm], degj = NBR_OFF[jm + 1] - offj;
                bool mem = false;
                for (int s = 0; s < degj; ++s) mem = mem || (NBR[offj + s] == nbr);
                if (mem) {
                    int ci = nbr * 8 + j;
                    v = w0[(size_t)(jm * 8 + (m & 7)) * 600 + ci * 3 + tap];
                }
            }
            wA0[(size_t)f * 512 + e] = (unsigned short)bfround(v);
        }
    } else if (bid < NF1 + 76 + 44) {              // shortcut weights
        const int f  = bid - NF1 - 76;
        const int jo = FRAG_SJ[f];
        const int mf = f - FBS[jo];
        const int off = NBR_OFF[jo];
        const int deg = NBR_OFF[jo + 1] - off;
        for (int e = threadIdx.x; e < 512; e += 256) {
            int lane = e >> 3, j = e & 7;
            int m = lane & 15, kb = lane >> 4;
            int c8 = mf * 4 + kb;
            float v = 0.f;
            if (c8 < deg) {
                int ci = NBR[off + c8] * 8 + j;
                v = wsc[(size_t)(jo * 16 + m) * 200 + ci];
            }
            wAs[(size_t)f * 512 + e] = (unsigned short)bfround(v);
        }
    } else {                                       // descriptors
        for (int e = threadIdx.x; e < DSC_TOT; e += 256) {
            if (e < DSC_SC) {
                int f = e >> 2, q = e & 3;
                int p = FRAG_P[f], mf = f - FB0[p];
                int puo = PUOFF[p], u = PUOFF[p + 1] - puo;
                int c8 = mf * 4 + q;
                int tp = 0, ni = 0;
                if (c8 < 3 * u) {
                    tp = (c8 >= 2 * u) ? 2 : ((c8 >= u) ? 1 : 0);
                    ni = c8 - tp * u;
                }
                dsc[e] = (tp << 12) | (PU[puo + ni] * 16);
            } else if (e < DSC_C1) {
                int e2 = e - DSC_SC;
                int f = e2 >> 2, q = e2 & 3;
                int jo = FRAG_SJ[f], mf = f - FBS[jo];
                int off = NBR_OFF[jo], deg = NBR_OFF[jo + 1] - off;
                int c8 = mf * 4 + q;
                int ni = (c8 < deg) ? c8 : deg - 1;
                dsc[e] = NBR[off + ni] * 16;
            } else {
                int e2 = e - DSC_C1;
                int f = e2 >> 2, q = e2 & 3;
                int jo = f / 7, mf = f - jo * 7;
                int off = NBR_OFF[jo], deg = NBR_OFF[jo + 1] - off;
                int c8 = mf * 4 + q;
                int tp = 0, ni = 0;
                if (c8 < 3 * deg) {
                    tp = (c8 >= 2 * deg) ? 2 : ((c8 >= deg) ? 1 : 0);
                    ni = c8 - tp * deg;
                }
                int rowd = (tp == 1) ? 33 : (tp >> 1);
                dsc[e] = rowd * CROWB + NBR[off + ni] * 16;
            }
        }
    }
}

// ------- Kernel A: conv0 + PReLU + shortcut via MFMA; 8-wave, 4 subtiles per A ---
// grid (128, 16), block 512 (8 waves = 8 pool groups; each wave all 4 subtiles).
__global__ __launch_bounds__(512) void conv0s_mfma(
    const float* __restrict__ x, const unsigned short* __restrict__ wA0,
    const unsigned short* __restrict__ wAs, const int* __restrict__ dsc,
    const float* __restrict__ b0, const float* __restrict__ a0,
    const float* __restrict__ bsc,
    unsigned short* __restrict__ h0T, unsigned short* __restrict__ sbu)
{
    __shared__ __align__(16) unsigned short xs[66 * 264];
    __shared__ int dl[DSC_C1];
    __shared__ float b0l[CIN], bscl[COUTC];
    const int b   = blockIdx.y;
    const int t0  = blockIdx.x * 64;
    const int tid = threadIdx.x;

    for (int i = tid; i < DSC_C1; i += 512) dl[i] = dsc[i];
    for (int i = tid; i < CIN; i += 512) b0l[i] = b0[i];
    for (int i = tid; i < COUTC; i += 512) bscl[i] = bsc[i];

    // ---- fused staging: x fp32 [c][t] -> xs bf16 [t=row][c], rows 0..65 ----
    const float* xb = x + (size_t)b * CIN * T1;
    // main rows 1..64: 8 channels x 4 t per thread, uint4 (16B) writes
    for (int e = tid; e < (CIN / 8) * 16; e += 512) {
        int c8i = e >> 4, k = e & 15;
        const float* xc = xb + (size_t)(8 * c8i) * T1 + t0 + 4 * k;
        float4 v0 = *(const float4*)(xc);
        float4 v1 = *(const float4*)(xc + T1);
        float4 v2 = *(const float4*)(xc + 2 * T1);
        float4 v3 = *(const float4*)(xc + 3 * T1);
        float4 v4 = *(const float4*)(xc + 4 * T1);
        float4 v5 = *(const float4*)(xc + 5 * T1);
        float4 v6 = *(const float4*)(xc + 6 * T1);
        float4 v7 = *(const float4*)(xc + 7 * T1);
        char* base = (char*)xs + 16 * c8i + (4 * k + 1) * CROWB;
        *(uint4*)(base) = make_uint4(packbf(v0.x, v1.x), packbf(v2.x, v3.x),
                                     packbf(v4.x, v5.x), packbf(v6.x, v7.x));
        *(uint4*)(base + CROWB) = make_uint4(packbf(v0.y, v1.y), packbf(v2.y, v3.y),
                                             packbf(v4.y, v5.y), packbf(v6.y, v7.y));
        *(uint4*)(base + 2 * CROWB) = make_uint4(packbf(v0.z, v1.z), packbf(v2.z, v3.z),
                                                 packbf(v4.z, v5.z), packbf(v6.z, v7.z));
        *(uint4*)(base + 3 * CROWB) = make_uint4(packbf(v0.w, v1.w), packbf(v2.w, v3.w),
                                                 packbf(v4.w, v5.w), packbf(v6.w, v7.w));
    }
    // halo rows 0 (t0-1) and 65 (t0+64), reflect-clamped
    for (int e = tid; e < 2 * CIN; e += 512) {
        int c = e >> 1, h = e & 1;
        int t = h ? (t0 + 64) : (t0 - 1);
        t = (t < 0) ? 1 : ((t >= T1) ? (2 * T1 - 2 - t) : t);
        float v = xb[(size_t)c * T1 + t];
        *(unsigned short*)((char*)xs + (h ? 65 : 0) * CROWB + 2 * c) = (unsigned short)bfround(v);
    }
    __syncthreads();

    const int w = tid >> 6, lane = tid & 63;
    const int q = lane >> 4, n = lane & 15;
    const float alpha = a0[0];
    char* xsb = (char*)xs + n * CROWB;

    // ---- conv0: pool group GB8[w]..GB8[w+1] x rotating depth-2 (A+B) x 4 subtiles
    unsigned h0k[2][4][2];
    const int g0 = GB8[w], g1 = GB8[w + 1];
    for (int gi = g0, pl = 0; gi < g1; ++gi, ++pl) {
        const int p = POOL_ORD[gi];
        const int fb = FB0[p], nmf = PNMF[p];
        const unsigned short* wAb = wA0 + (size_t)fb * 512;
        f32x4 acc0 = {0.f, 0.f, 0.f, 0.f};
        f32x4 acc1 = {0.f, 0.f, 0.f, 0.f};
        f32x4 acc2 = {0.f, 0.f, 0.f, 0.f};
        f32x4 acc3 = {0.f, 0.f, 0.f, 0.f};
        bf16x8 aCur = *(const bf16x8*)(wAb + (size_t)lane * 8);
        int d = dl[fb * 4 + q];
        char* bp = xsb + (d >> 12) * CROWB + (d & 0xFFF);
        bf16x8 B0c = *(const bf16x8*)(bp);
        bf16x8 B1c = *(const bf16x8*)(bp + 16 * CROWB);
        bf16x8 B2c = *(const bf16x8*)(bp + 32 * CROWB);
        bf16x8 B3c = *(const bf16x8*)(bp + 48 * CROWB);
        for (int mf = 0; mf < nmf; ++mf) {
            int m2 = (mf + 1 < nmf) ? mf + 1 : mf;
            bf16x8 aNxt = *(const bf16x8*)(wAb + ((size_t)m2 * 64 + lane) * 8);
            d = dl[(fb + m2) * 4 + q];
            char* bpn = xsb + (d >> 12) * CROWB + (d & 0xFFF);
            bf16x8 B0n = *(const bf16x8*)(bpn);
            bf16x8 B1n = *(const bf16x8*)(bpn + 16 * CROWB);
            bf16x8 B2n = *(const bf16x8*)(bpn + 32 * CROWB);
            bf16x8 B3n = *(const bf16x8*)(bpn + 48 * CROWB);
            acc0 = __builtin_amdgcn_mfma_f32_16x16x32_bf16(aCur, B0c, acc0, 0, 0, 0);
            acc1 = __builtin_amdgcn_mfma_f32_16x16x32_bf16(aCur, B1c, acc1, 0, 0, 0);
            acc2 = __builtin_amdgcn_mfma_f32_16x16x32_bf16(aCur, B2c, acc2, 0, 0, 0);
            acc3 = __builtin_amdgcn_mfma_f32_16x16x32_bf16(aCur, B3c, acc3, 0, 0, 0);
            aCur = aNxt;
            B0c = B0n; B1c = B1n; B2c = B2n; B3c = B3n;
        }
        int jm = (q < 2) ? PAIR_A[p] : PAIR_B[p];
        if (jm >= 0) {
            int ocb = (q & 1) * 4;
            float bb0 = b0l[jm * 8 + ocb + 0], bb1 = b0l[jm * 8 + ocb + 1];
            float bb2 = b0l[jm * 8 + ocb + 2], bb3 = b0l[jm * 8 + ocb + 3];
            f32x4 aa[4] = {acc0, acc1, acc2, acc3};
#pragma unroll
            for (int s = 0; s < 4; ++s) {
                float v0 = aa[s][0] + bb0; v0 = (v0 >= 0.f) ? v0 : alpha * v0;
                float v1 = aa[s][1] + bb1; v1 = (v1 >= 0.f) ? v1 : alpha * v1;
                float v2 = aa[s][2] + bb2; v2 = (v2 >= 0.f) ? v2 : alpha * v2;
                float v3 = aa[s][3] + bb3; v3 = (v3 >= 0.f) ? v3 : alpha * v3;
                h0k[pl][s][0] = packbf(v0, v1);
                h0k[pl][s][1] = packbf(v2, v3);
            }
        }
    }

    // ---- shortcut: joints mod 8 per wave, rotating depth-2, both ns-halves ----
    for (int jo = w; jo < NJ; jo += 8) {
        const int fb = FBS[jo], nsf = NSF[jo];
        const unsigned short* wAb = wAs + (size_t)fb * 512;
        const int dbase = DSC_SC + fb * 4 + q;
        char* rb0 = (char*)xs + (2 * n + 1) * CROWB;
        f32x4 acc0 = {0.f, 0.f, 0.f, 0.f};
        f32x4 acc1 = {0.f, 0.f, 0.f, 0.f};
        int i1 = (nsf > 1) ? 1 : 0;
        bf16x8 af0 = *(const bf16x8*)(wAb + (size_t)lane * 8);
        int d = dl[dbase];
        bf16x8 b0v = *(const bf16x8*)(rb0 + d);
        bf16x8 b1v = *(const bf16x8*)(rb0 + d + 32 * CROWB);
        bf16x8 af1 = *(const bf16x8*)(wAb + ((size_t)i1 * 64 + lane) * 8);
        d = dl[dbase + i1 * 4];
        bf16x8 b0n = *(const bf16x8*)(rb0 + d);
        bf16x8 b1n = *(const bf16x8*)(rb0 + d + 32 * CROWB);
        for (int mf = 0; mf < nsf; ++mf) {
            int m2 = (mf + 2 < nsf) ? mf + 2 : nsf - 1;
            bf16x8 a2 = *(const bf16x8*)(wAb + ((size_t)m2 * 64 + lane) * 8);
            d = dl[dbase + m2 * 4];
            bf16x8 b02 = *(const bf16x8*)(rb0 + d);
            bf16x8 b12 = *(const bf16x8*)(rb0 + d + 32 * CROWB);
            acc0 = __builtin_amdgcn_mfma_f32_16x16x32_bf16(af0, b0v, acc0, 0, 0, 0);
            acc1 = __builtin_amdgcn_mfma_f32_16x16x32_bf16(af0, b1v, acc1, 0, 0, 0);
            af0 = af1; af1 = a2;
            b0v = b0n; b0n = b02;
            b1v = b1n; b1n = b12;
        }
        unsigned short* sp = sbu + ((size_t)b * COUTC + jo * 16 + q * 4) * TT2 + (t0 >> 1) + n;
#pragma unroll
        for (int r = 0; r < 4; ++r) {
            float bsv = bscl[jo * 16 + q * 4 + r];
            sp[(size_t)r * TT2]      = (unsigned short)bfround(acc0[r] + bsv);
            sp[(size_t)r * TT2 + 16] = (unsigned short)bfround(acc1[r] + bsv);
        }
    }

    // ---- write h0 tile into xs as [t][c] (uint2 8B writes), store h0T coalesced --
    __syncthreads();
    for (int gi = g0, pl = 0; gi < g1; ++gi, ++pl) {
        int p = POOL_ORD[gi];
        int jm = (q < 2) ? PAIR_A[p] : PAIR_B[p];
        if (jm >= 0) {
            int cb = (jm * 8 + (q & 1) * 4) * 2;
#pragma unroll
            for (int s = 0; s < 4; ++s)
                *(uint2*)((char*)xs + (16 * s + n) * CROWB + cb) =
                    make_uint2(h0k[pl][s][0], h0k[pl][s][1]);
        }
    }
    __syncthreads();
    unsigned short* ho = h0T + ((size_t)b * T1 + t0 + w * 8) * CIN;
    for (int e = lane; e < 8 * 25; e += 64) {
        int row = e / 25, k = e - row * 25;
        uint4 u = *(const uint4*)((char*)xs + (w * 8 + row) * CROWB + 16 * k);
        *(uint4*)(ho + (size_t)row * CIN + 8 * k) = u;
    }
}

// ------- Kernel B: conv1 via MFMA + GN partials; 8-wave blocks -------------------
// grid (128, 16), block 512 (8 waves = joint groups; each wave both t2-subtiles).
__global__ __launch_bounds__(512) void conv1_mfma(
    const unsigned short* __restrict__ h0T, const unsigned short* __restrict__ wA,
    const int* __restrict__ dsc, const float* __restrict__ b1,
    unsigned short* __restrict__ h1u, float* __restrict__ part)
{
    __shared__ __align__(16) unsigned short xs[65 * 264];   // odd rows 0..32, even 33..64
    __shared__ int dl1[NF1 * 4];
    __shared__ float biasl[COUTC];
    const int b   = blockIdx.y;
    const int t20 = blockIdx.x * 32;
    const int tid = threadIdx.x;

    for (int i = tid; i < NF1 * 4; i += 512) dl1[i] = dsc[DSC_C1 + i];
    for (int i = tid; i < COUTC; i += 512) biasl[i] = b1[i];

    const unsigned short* hTb = h0T + (size_t)b * T1 * CIN;
    for (int e = tid; e < 65 * 25; e += 512) {
        int row = e / 25, k = e - row * 25;
        int p = (row < 33) ? (2 * t20 - 1 + 2 * row) : (2 * t20 + 2 * (row - 33));
        if (p < 0) p = 1;
        uint4 u = *(const uint4*)(hTb + (size_t)p * CIN + 8 * k);
        *(uint4*)((char*)xs + row * CROWB + 16 * k) = u;
    }
    __syncthreads();

    const int w = tid >> 6, lane = tid & 63;
    const int q = lane >> 4, n = lane & 15;
    const int j0 = JSPLIT8[w], j1 = JSPLIT8[w + 1];
    const int t2gA = t20 + n, t2gB = t20 + 16 + n;
    char* xsb = (char*)xs + n * CROWB;

    for (int jo = j0; jo < j1; ++jo) {
        const unsigned short* wAb = wA + (size_t)(jo * 7) * 512;
        const int dbase = jo * 28 + q;
        f32x4 acc0 = {0.f, 0.f, 0.f, 0.f};
        f32x4 acc1 = {0.f, 0.f, 0.f, 0.f};
#pragma unroll
        for (int mf = 0; mf < 7; ++mf) {
            bf16x8 a = *(const bf16x8*)(wAb + ((size_t)mf * 64 + lane) * 8);
            int d = dl1[dbase + mf * 4];
            bf16x8 bb0 = *(const bf16x8*)(xsb + d);
            bf16x8 bb1 = *(const bf16x8*)(xsb + d + 16 * CROWB);
            acc0 = __builtin_amdgcn_mfma_f32_16x16x32_bf16(a, bb0, acc0, 0, 0, 0);
            acc1 = __builtin_amdgcn_mfma_f32_16x16x32_bf16(a, bb1, acc1, 0, 0, 0);
        }

        float s = 0.f, ss = 0.f;
        unsigned short* hout = h1u + ((size_t)b * COUTC + jo * 16) * TT2;
#pragma unroll
        for (int r = 0; r < 4; ++r) {
            int oc = q * 4 + r;
            float bv = biasl[jo * 16 + oc];
            float v0 = acc0[r] + bv;
            float v1 = acc1[r] + bv;
            s += v0 + v1; ss += v0 * v0 + v1 * v1;
            hout[(size_t)oc * TT2 + t2gA] = (unsigned short)bfround(v0);
            hout[(size_t)oc * TT2 + t2gB] = (unsigned short)bfround(v1);
        }
        for (int o2 = 1; o2 < 32; o2 <<= 1) {
            s  += __shfl_xor(s, o2, 64);
            ss += __shfl_xor(ss, o2, 64);
        }
        if ((lane & 31) == 0) {
            int half = lane >> 5;
            size_t o = (((size_t)b * 50 + jo * 2 + half) * 128 + blockIdx.x) * 2;
            part[o] = s; part[o + 1] = ss;
        }
    }
}

// ------- finalize stats + per-(b,ch) GN coefficients (merged) --------------------
__global__ __launch_bounds__(256) void gn_final2(const float* __restrict__ part,
                                                 const float* __restrict__ gamma,
                                                 const float* __restrict__ beta,
                                                 float* __restrict__ AB)
{
    const int bg = blockIdx.x;
    const int b = bg / NGROUP, g = bg % NGROUP;
    float s = 0.f, ss = 0.f;
    for (int k = threadIdx.x; k < 5 * 128; k += 256) {
        int sb = k >> 7, slot = k & 127;
        size_t o = (((size_t)b * 50 + g * 5 + sb) * 128 + slot) * 2;
        s += part[o]; ss += part[o + 1];
    }
    for (int o2 = 32; o2; o2 >>= 1) {
        s  += __shfl_down(s, o2, 64);
        ss += __shfl_down(ss, o2, 64);
    }
    __shared__ float rs[4], rss[4];
    __shared__ float sm[2];
    const int lane = threadIdx.x & 63, wv = threadIdx.x >> 6;
    if (lane == 0) { rs[wv] = s; rss[wv] = ss; }
    __syncthreads();
    if (threadIdx.x == 0) {
        float S  = rs[0] + rs[1] + rs[2] + rs[3];
        float SS = rss[0] + rss[1] + rss[2] + rss[3];
        const float invN = 1.0f / (float)(CPG * TT2);
        float mean = S * invN;
        float var  = SS * invN - mean * mean;
        sm[0] = mean;
        sm[1] = rsqrtf(var + 1e-5f);
    }
    __syncthreads();
    if (threadIdx.x < CPG) {
        int ch = g * CPG + threadIdx.x;
        float A = sm[1] * gamma[ch];
        AB[((size_t)b * COUTC + ch) * 2]     = A;
        AB[((size_t)b * COUTC + ch) * 2 + 1] = beta[ch] - sm[0] * A;
    }
}

// ------- Kernel E: streaming GN-apply + add s + pool + PReLU ---------------------
__global__ __launch_bounds__(256) void final2pb(
    const unsigned* __restrict__ h1b, const unsigned* __restrict__ sb,
    const float* __restrict__ AB, const float* __restrict__ a1,
    float* __restrict__ outb)
{
    const int n     = blockIdx.y >> 1;
    const int chalf = blockIdx.y & 1;
    const int b     = blockIdx.z;
    const int tid   = threadIdx.x;
    const int t0    = (blockIdx.x * 256 + tid) * 4;

    int js[2];
    js[0] = PAIR_A[n];
    const int jb = PAIR_B[n];
    const int L = (jb >= 0) ? 2 : 1;
    js[1] = (jb >= 0) ? jb : js[0];

    __shared__ float Al[2][8], Bl[2][8];
    if (tid < 16) {
        int ji = tid >> 3, c8 = tid & 7;
        int ch = js[ji] * 16 + chalf * 8 + c8;
        Al[ji][c8] = AB[((size_t)b * COUTC + ch) * 2];
        Bl[ji][c8] = AB[((size_t)b * COUTC + ch) * 2 + 1];
    }
    __syncthreads();

    const float alpha = a1[0];
    const float invL  = (L == 2) ? 0.5f : 1.0f;

    float acc[8][4];
#pragma unroll
    for (int c = 0; c < 8; ++c)
#pragma unroll
        for (int i = 0; i < 4; ++i) acc[c][i] = 0.f;

    for (int ji = 0; ji < L; ++ji) {
        const int jc0 = js[ji] * 16 + chalf * 8;
#pragma unroll
        for (int c = 0; c < 8; ++c) {
            size_t rowoff = ((size_t)b * COUTC + jc0 + c) * (TT2 / 2) + t0 / 2;
            uint2 hv = *(const uint2*)(h1b + rowoff);
            uint2 sv = *(const uint2*)(sb + rowoff);
            float A = Al[ji][c], Bc = Bl[ji][c];
            acc[c][0] += bflo(hv.x) * A + Bc + bflo(sv.x);
            acc[c][1] += bfhi(hv.x) * A + Bc + bfhi(sv.x);
            acc[c][2] += bflo(hv.y) * A + Bc + bflo(sv.y);
            acc[c][3] += bfhi(hv.y) * A + Bc + bfhi(sv.y);
        }
    }

    float* ob = outb + ((size_t)b * 224 + n * 16 + chalf * 8) * TT2 + t0;
#pragma unroll
    for (int c = 0; c < 8; ++c) {
        float4 o;
#pragma unroll
        for (int i = 0; i < 4; ++i) {
            float v = acc[c][i] * invL;
            ((float*)&o)[i] = (v >= 0.f) ? v : alpha * v;
        }
        *(float4*)(ob + (size_t)c * TT2) = o;
    }
}

extern "C" void kernel_launch(void* const* d_in, const int* in_sizes, int n_in,
                              void* d_out, int out_size, void* d_ws, size_t ws_size,
                              hipStream_t stream) {
    const float* x     = (const float*)d_in[0];
    const float* w0    = (const float*)d_in[1];
    const float* b0    = (const float*)d_in[2];
    const float* a0    = (const float*)d_in[3];
    const float* w1    = (const float*)d_in[4];
    const float* b1    = (const float*)d_in[5];
    const float* gamma = (const float*)d_in[6];
    const float* beta  = (const float*)d_in[7];
    const float* wsc   = (const float*)d_in[8];
    const float* bsc   = (const float*)d_in[9];
    const float* a1    = (const float*)d_in[10];
    float* out = (float*)d_out;

    const size_t NB = (size_t)BATCH * CIN * T1;   // 26,214,400 elements
    unsigned short* h0T  = (unsigned short*)d_ws;
    unsigned short* sbu  = h0T + NB;
    unsigned short* h1u  = sbu + NB;
    unsigned short* wA1  = h1u + NB;                              // 175*512
    unsigned short* wA0p = wA1 + (size_t)NF1 * 512;               // 76*512
    unsigned short* wAsp = wA0p + (size_t)76 * 512;               // 44*512
    int* dsc     = (int*)(wAsp + (size_t)44 * 512);               // 1180 ints
    float* part  = (float*)(dsc + DSC_TOT);                       // 16*50*128*2
    float* AB    = part + (size_t)BATCH * 50 * 128 * 2;

    prep_all<<<dim3(NF1 + 76 + 44 + 1), 256, 0, stream>>>(w1, w0, wsc, wA1, wA0p, wAsp, dsc);
    conv0s_mfma<<<dim3(T1 / 64, BATCH), 512, 0, stream>>>(x, wA0p, wAsp, dsc, b0, a0, bsc, h0T, sbu);
    conv1_mfma<<<dim3(TT2 / 32, BATCH), 512, 0, stream>>>(h0T, wA1, dsc, b1, h1u, part);
    gn_final2<<<dim3(BATCH * NGROUP), 256, 0, stream>>>(part, gamma, beta, AB);
    final2pb<<<dim3(TT2 / 1024, NPOOL * 2, BATCH), 256, 0, stream>>>((const unsigned*)h1u,
                                                                     (const unsigned*)sbu, AB, a1, out);
}